// Round 9
// baseline (291.416 us; speedup 1.0000x reference)
//
#include <hip/hip_runtime.h>

#define NNODE 10000
#define NEDGE 160000

using frag8 = __attribute__((ext_vector_type(8))) short;
using f32x4 = __attribute__((ext_vector_type(4))) float;

__device__ __forceinline__ unsigned short f2bf(float f) {
    union { float f; unsigned u; } v; v.f = f;
    unsigned r = (v.u + 0x7fffu + ((v.u >> 16) & 1u)) >> 16;
    return (unsigned short)r;
}
__device__ __forceinline__ float bf2f(unsigned short s) {
    union { unsigned u; float f; } v; v.u = ((unsigned)s) << 16; return v.f;
}

// ---------------- scan ----------------
__global__ __launch_bounds__(1024) void k_scan(const int* __restrict__ deg,
                                               int* __restrict__ rs,
                                               int* __restrict__ cur, int n, int total) {
    const int tid = threadIdx.x;
    const int CH = 10;
    const int base = tid * CH;
    int vals[CH];
    int tsum = 0;
#pragma unroll
    for (int j = 0; j < CH; j++) {
        int v = (base + j < n) ? deg[base + j] : 0;
        vals[j] = v; tsum += v;
    }
    const int lane = tid & 63, wid = tid >> 6;
    int x = tsum;
#pragma unroll
    for (int d = 1; d < 64; d <<= 1) {
        int y = __shfl_up(x, d, 64);
        if (lane >= d) x += y;
    }
    __shared__ int wt[16];
    if (lane == 63) wt[wid] = x;
    __syncthreads();
    if (tid == 0) {
        int c = 0;
#pragma unroll
        for (int k = 0; k < 16; k++) { int t = wt[k]; wt[k] = c; c += t; }
    }
    __syncthreads();
    int run = wt[wid] + x - tsum;
#pragma unroll
    for (int j = 0; j < CH; j++) {
        if (base + j < n) { rs[base + j] = run; cur[base + j] = run; }
        run += vals[j];
    }
    if (tid == 0) rs[n] = total;
}

__global__ void k_fill(const int* __restrict__ src, const int* __restrict__ dst,
                       int E, int* __restrict__ cur, int* __restrict__ csr) {
    int e = blockIdx.x * 256 + threadIdx.x;
    if (e < E) {
        int p = atomicAdd(&cur[dst[e]], 1);
        csr[p] = src[e];
    }
}

// ---------------- fused prep: x-cast + weight transposes + scale/shift + edge count ----------------
__global__ __launch_bounds__(256) void k_prep(
    const float* __restrict__ x, unsigned short* __restrict__ xb,
    const float* __restrict__ wl1, const float* __restrict__ wr1,
    const float* __restrict__ wl2, const float* __restrict__ wr2,
    const float* __restrict__ wl3, const float* __restrict__ wr3,
    unsigned short* __restrict__ bt1, unsigned short* __restrict__ bt2,
    unsigned short* __restrict__ bt3,
    const float* __restrict__ b1, const float* __restrict__ g1, const float* __restrict__ be1,
    const float* __restrict__ m1, const float* __restrict__ v1,
    const float* __restrict__ b2, const float* __restrict__ g2, const float* __restrict__ be2,
    const float* __restrict__ m2, const float* __restrict__ v2,
    const float* __restrict__ b3,
    float* __restrict__ sc1, float* __restrict__ sh1,
    float* __restrict__ sc2, float* __restrict__ sh2,
    float* __restrict__ sc3, float* __restrict__ sh3,
    const int* __restrict__ dstI, int* __restrict__ deg) {
    const int b = blockIdx.x, tid = threadIdx.x;
    if (b < 5000) {                       // x cast
        int i = b * 256 + tid;
        float4 f = ((const float4*)x)[i];
        ushort4 o;
        o.x = f2bf(f.x); o.y = f2bf(f.y); o.z = f2bf(f.z); o.w = f2bf(f.w);
        ((ushort4*)xb)[i] = o;
        return;
    }
    if (b >= 6281) {                      // edge degree count
        int e = (b - 6281) * 256 + tid;
        if (e < NEDGE) atomicAdd(&deg[dstI[e]], 1);
        return;
    }
    if (b == 6280) {                      // scale/shift
        for (int t = tid; t < 512; t += 256) {
            float s1 = g1[t] * rsqrtf(v1[t] + 1e-5f);
            sc1[t] = s1; sh1[t] = (b1[t] - m1[t]) * s1 + be1[t];
            float s2 = g2[t] * rsqrtf(v2[t] + 1e-5f);
            sc2[t] = s2; sh2[t] = (b2[t] - m2[t]) * s2 + be2[t];
        }
        if (tid < 256) { sc3[tid] = 1.0f; sh3[tid] = b3[tid]; }
        return;
    }
    __shared__ float t[32][33];
    int tj = b - 5000;
    const float* srcp; unsigned short* dstp; int C, koff, ntilesN;
    if (tj < 1024) {
        int job = tj >> 8; int tile = tj & 255; C = 512; ntilesN = 16;
        srcp = (job == 0) ? wl1 : (job == 1) ? wr1 : (job == 2) ? wl2 : wr2;
        dstp = (job < 2) ? bt1 : bt2; koff = (job & 1) * 512;
        tj = tile;
    } else {
        int jj = tj - 1024; int job = jj >> 7; int tile = jj & 127; C = 256; ntilesN = 8;
        srcp = (job == 0) ? wl3 : wr3; dstp = bt3; koff = job * 512;
        tj = tile;
    }
    int k0 = (tj / ntilesN) * 32, c0 = (tj % ntilesN) * 32;
    int tx = tid & 31, ty = tid >> 5;
#pragma unroll
    for (int q = 0; q < 4; q++)
        t[ty + 8 * q][tx] = srcp[(long)(k0 + ty + 8 * q) * C + c0 + tx];
    __syncthreads();
#pragma unroll
    for (int q = 0; q < 4; q++)
        dstp[(long)(c0 + ty + 8 * q) * 1024 + koff + k0 + tx] = f2bf(t[tx][ty + 8 * q]);
}

// ---------------- aggregation: column-partitioned, XCD-affine ----------------
// Block b: XCD (b&7) owns 64 cols [64*X, 64*X+64). Slice = 10000*64*2B = 1.28MB -> L2-resident,
// all 160K edges reuse it (16x). Half-waves process 2 neighbors/step (lane = 4B = 2 cols).
__global__ __launch_bounds__(256) void k_agg(const unsigned short* __restrict__ S,
                                             const int* __restrict__ rs, const int* __restrict__ csr,
                                             unsigned short* __restrict__ outb) {
    const int X = blockIdx.x & 7;
    const int grp = blockIdx.x >> 3;          // 0..255
    const int wave = threadIdx.x >> 6;
    const int lane = threadIdx.x & 63;
    const int half = lane >> 5;
    const int c = X * 64 + (lane & 31) * 2;
    for (int n = grp * 4 + wave; n < NNODE; n += 1024) {
        const int s = rs[n], e = rs[n + 1];
        float a0 = 0.f, a1 = 0.f;
        int i = s;
        for (; i + 4 <= e; i += 4) {
            int s0 = csr[i + half], s1 = csr[i + 2 + half];
            unsigned u0 = *(const unsigned*)(S + (long)s0 * 512 + c);
            unsigned u1 = *(const unsigned*)(S + (long)s1 * 512 + c);
            a0 += bf2f((unsigned short)(u0 & 0xffffu)) + bf2f((unsigned short)(u1 & 0xffffu));
            a1 += bf2f((unsigned short)(u0 >> 16)) + bf2f((unsigned short)(u1 >> 16));
        }
        for (; i < e; i += 2) {
            int j = i + half;
            if (j < e) {
                int sj = csr[j];
                unsigned u = *(const unsigned*)(S + (long)sj * 512 + c);
                a0 += bf2f((unsigned short)(u & 0xffffu));
                a1 += bf2f((unsigned short)(u >> 16));
            }
        }
        a0 += __shfl_xor(a0, 32, 64);
        a1 += __shfl_xor(a1, 32, 64);
        const int cnt = e - s;
        const float inv = 1.f / (float)(cnt > 1 ? cnt : 1);
        if (half == 0) {
            unsigned o = (unsigned)f2bf(a0 * inv) | ((unsigned)f2bf(a1 * inv) << 16);
            *(unsigned*)(outb + (long)n * 512 + c) = o;
        }
    }
}

// ---------------- GEMM: 128x128 tile, 4x4 frags/wave, LDS dbuf (1 barrier/iter), XCD swizzle ----------------
// C[M x NOUT] = [Agg|Self][M x 1024] @ Bt[NOUT x 1024]^T, BK=64.
// MODE 0: relu(dot*sc+sh) -> bf16 stride 512 ; MODE 1: dot*sc+sh -> fp32 stride NOUT.
template <int MODE, int NOUT>
__global__ __launch_bounds__(256, 2) void k_gemm(const unsigned short* __restrict__ Agg,
                                                 const unsigned short* __restrict__ Self,
                                                 const unsigned short* __restrict__ Bt,
                                                 const float* __restrict__ sc, const float* __restrict__ sh,
                                                 unsigned short* __restrict__ hout, float* __restrict__ fout,
                                                 int M) {
    constexpr int NT = NOUT / 128;          // n-tiles: 4 or 2
    constexpr int QSH = (NT == 4) ? 5 : 4;  // 3 + log2(NT)
    const int b = blockIdx.x;
    const int X = b & 7;
    const int q = (b >> 3) & (NT - 1);
    const int g = b >> QSH;
    const int m0 = (g * 8 + X) * 128;
    if (m0 >= M) return;
    const int n0 = q * 128;

    __shared__ __align__(16) short As[2][128 * 64];   // 32 KB
    __shared__ __align__(16) short Bs[2][128 * 64];   // 32 KB
    const int tid = threadIdx.x;
    const int w = tid >> 6, lane = tid & 63;
    const int wm = (w >> 1) * 64, wn = (w & 1) * 64;
    const int fr = lane & 15, fq = lane >> 4, sw = fr & 7;
    const int srow = w * 8 + (lane >> 3);
    const int scol = (((lane & 7) ^ (lane >> 3)) * 8);
    const int ldsOff = w * 8 * 64;

    f32x4 acc[4][4];
#pragma unroll
    for (int i = 0; i < 4; i++)
#pragma unroll
        for (int j = 0; j < 4; j++)
#pragma unroll
            for (int r = 0; r < 4; r++) acc[i][j][r] = 0.f;

    auto issue = [&](int t, int buf) {
        const short* abase = (const short*)((t < 8) ? Agg : Self);
        const int kk = (t & 7) * 64;
        const int k0 = t * 64;
#pragma unroll
        for (int cch = 0; cch < 4; cch++) {
            __builtin_amdgcn_global_load_lds(
                (const __attribute__((address_space(1))) void*)(abase + (long)(m0 + cch * 32 + srow) * 512 + kk + scol),
                (__attribute__((address_space(3))) void*)(&As[buf][ldsOff + cch * 32 * 64]), 16, 0, 0);
            __builtin_amdgcn_global_load_lds(
                (const __attribute__((address_space(1))) void*)((const short*)Bt + (long)(n0 + cch * 32 + srow) * 1024 + k0 + scol),
                (__attribute__((address_space(3))) void*)(&Bs[buf][ldsOff + cch * 32 * 64]), 16, 0, 0);
        }
    };

    issue(0, 0);
#pragma unroll
    for (int t = 0; t < 16; t++) {
        const int cur = t & 1;
        __syncthreads();
        if (t < 15) issue(t + 1, cur ^ 1);
#pragma unroll
        for (int ks = 0; ks < 2; ks++) {
            frag8 af[4], bf[4];
#pragma unroll
            for (int i = 0; i < 4; i++)
                af[i] = *(const frag8*)(&As[cur][(wm + i * 16 + fr) * 64 + (((ks * 4 + fq) ^ sw) * 8)]);
#pragma unroll
            for (int j = 0; j < 4; j++)
                bf[j] = *(const frag8*)(&Bs[cur][(wn + j * 16 + fr) * 64 + (((ks * 4 + fq) ^ sw) * 8)]);
#pragma unroll
            for (int i = 0; i < 4; i++)
#pragma unroll
                for (int j = 0; j < 4; j++)
                    acc[i][j] = __builtin_amdgcn_mfma_f32_16x16x32_bf16(af[i], bf[j], acc[i][j], 0, 0, 0);
        }
    }

    float scj[4], shj[4];
#pragma unroll
    for (int j = 0; j < 4; j++) {
        int col = n0 + wn + j * 16 + fr;
        scj[j] = sc[col]; shj[j] = sh[col];
    }
#pragma unroll
    for (int i = 0; i < 4; i++) {
        int rowb = m0 + wm + i * 16 + fq * 4;
#pragma unroll
        for (int j = 0; j < 4; j++) {
            int col = n0 + wn + j * 16 + fr;
#pragma unroll
            for (int r = 0; r < 4; r++) {
                int row = rowb + r;
                if (row < M) {
                    float y = acc[i][j][r] * scj[j] + shj[j];
                    if constexpr (MODE == 0) {
                        y = fmaxf(y, 0.f);
                        hout[(long)row * 512 + col] = f2bf(y);
                    } else {
                        fout[(long)row * NOUT + col] = y;
                    }
                }
            }
        }
    }
}

extern "C" void kernel_launch(void* const* d_in, const int* in_sizes, int n_in,
                              void* d_out, int out_size, void* d_ws, size_t ws_size,
                              hipStream_t stream) {
    const float* x    = (const float*)d_in[0];
    const int*   ei   = (const int*)d_in[1];
    const float* w_l1 = (const float*)d_in[2];
    const float* b1   = (const float*)d_in[3];
    const float* w_r1 = (const float*)d_in[4];
    const float* g1   = (const float*)d_in[5];
    const float* be1  = (const float*)d_in[6];
    const float* m1   = (const float*)d_in[7];
    const float* v1   = (const float*)d_in[8];
    const float* w_l2 = (const float*)d_in[9];
    const float* b2   = (const float*)d_in[10];
    const float* w_r2 = (const float*)d_in[11];
    const float* g2   = (const float*)d_in[12];
    const float* be2  = (const float*)d_in[13];
    const float* m2   = (const float*)d_in[14];
    const float* v2   = (const float*)d_in[15];
    const float* w_l3 = (const float*)d_in[16];
    const float* b3   = (const float*)d_in[17];
    const float* w_r3 = (const float*)d_in[18];
    float* out = (float*)d_out;

    const int N = NNODE, E = NEDGE;
    const int* srcI = ei;
    const int* dstI = ei + E;

    char* w = (char*)d_ws;
    auto alloc = [&](size_t bytes) { void* p = (void*)w; w += (bytes + 255) & ~(size_t)255; return p; };
    int* deg = (int*)alloc((size_t)N * 4);
    int* rs  = (int*)alloc((size_t)(N + 1) * 4);
    int* cur = (int*)alloc((size_t)N * 4);
    int* csr = (int*)alloc((size_t)E * 4);
    unsigned short* xb   = (unsigned short*)alloc((size_t)N * 512 * 2);
    unsigned short* bt1  = (unsigned short*)alloc((size_t)512 * 1024 * 2);
    unsigned short* bt2  = (unsigned short*)alloc((size_t)512 * 1024 * 2);
    unsigned short* bt3  = (unsigned short*)alloc((size_t)256 * 1024 * 2);
    float* sc1 = (float*)alloc(512 * 4); float* sh1 = (float*)alloc(512 * 4);
    float* sc2 = (float*)alloc(512 * 4); float* sh2 = (float*)alloc(512 * 4);
    float* sc3 = (float*)alloc(256 * 4); float* sh3 = (float*)alloc(256 * 4);
    unsigned short* agg_a = (unsigned short*)alloc((size_t)N * 512 * 2);
    unsigned short* h1    = (unsigned short*)alloc((size_t)N * 512 * 2);
    unsigned short* h2    = (unsigned short*)alloc((size_t)N * 512 * 2);
    (void)alloc(256 * 1024);  // DMA over-read slack for last M-tile

    hipMemsetAsync(deg, 0, (size_t)N * 4, stream);
    k_prep<<<6906, 256, 0, stream>>>(x, xb, w_l1, w_r1, w_l2, w_r2, w_l3, w_r3,
                                     bt1, bt2, bt3,
                                     b1, g1, be1, m1, v1, b2, g2, be2, m2, v2, b3,
                                     sc1, sh1, sc2, sh2, sc3, sh3, dstI, deg);
    k_scan<<<1, 1024, 0, stream>>>(deg, rs, cur, N, E);
    k_fill<<<(E + 255) / 256, 256, 0, stream>>>(srcI, dstI, E, cur, csr);

    // Layer 1
    k_agg<<<2048, 256, 0, stream>>>(xb, rs, csr, agg_a);
    k_gemm<0, 512><<<320, 256, 0, stream>>>(agg_a, xb, bt1, sc1, sh1, h1, nullptr, N);
    // Layer 2
    k_agg<<<2048, 256, 0, stream>>>(h1, rs, csr, agg_a);
    k_gemm<0, 512><<<320, 256, 0, stream>>>(agg_a, h1, bt2, sc2, sh2, h2, nullptr, N);
    // Layer 3
    k_agg<<<2048, 256, 0, stream>>>(h2, rs, csr, agg_a);
    k_gemm<1, 256><<<160, 256, 0, stream>>>(agg_a, h2, bt3, sc3, sh3, nullptr, out, N);
}

// Round 10
// 282.988 us; speedup vs baseline: 1.0298x; 1.0298x over previous
//
#include <hip/hip_runtime.h>

#define NNODE 10000
#define NEDGE 160000

using frag8 = __attribute__((ext_vector_type(8))) short;
using f32x4 = __attribute__((ext_vector_type(4))) float;

__device__ __forceinline__ unsigned short f2bf(float f) {
    union { float f; unsigned u; } v; v.f = f;
    unsigned r = (v.u + 0x7fffu + ((v.u >> 16) & 1u)) >> 16;
    return (unsigned short)r;
}
__device__ __forceinline__ float bf2f(unsigned short s) {
    union { unsigned u; float f; } v; v.u = ((unsigned)s) << 16; return v.f;
}

// ---------------- scan ----------------
__global__ __launch_bounds__(1024) void k_scan(const int* __restrict__ deg,
                                               int* __restrict__ rs,
                                               int* __restrict__ cur, int n, int total) {
    const int tid = threadIdx.x;
    const int CH = 10;
    const int base = tid * CH;
    int vals[CH];
    int tsum = 0;
#pragma unroll
    for (int j = 0; j < CH; j++) {
        int v = (base + j < n) ? deg[base + j] : 0;
        vals[j] = v; tsum += v;
    }
    const int lane = tid & 63, wid = tid >> 6;
    int x = tsum;
#pragma unroll
    for (int d = 1; d < 64; d <<= 1) {
        int y = __shfl_up(x, d, 64);
        if (lane >= d) x += y;
    }
    __shared__ int wt[16];
    if (lane == 63) wt[wid] = x;
    __syncthreads();
    if (tid == 0) {
        int c = 0;
#pragma unroll
        for (int k = 0; k < 16; k++) { int t = wt[k]; wt[k] = c; c += t; }
    }
    __syncthreads();
    int run = wt[wid] + x - tsum;
#pragma unroll
    for (int j = 0; j < CH; j++) {
        if (base + j < n) { rs[base + j] = run; cur[base + j] = run; }
        run += vals[j];
    }
    if (tid == 0) rs[n] = total;
}

__global__ void k_fill(const int* __restrict__ src, const int* __restrict__ dst,
                       int E, int* __restrict__ cur, int* __restrict__ csr) {
    int e = blockIdx.x * 256 + threadIdx.x;
    if (e < E) {
        int p = atomicAdd(&cur[dst[e]], 1);
        csr[p] = src[e];
    }
}

// ---------------- fused prep: x-cast + weight transposes + scale/shift + edge count ----------------
__global__ __launch_bounds__(256) void k_prep(
    const float* __restrict__ x, unsigned short* __restrict__ xb,
    const float* __restrict__ wl1, const float* __restrict__ wr1,
    const float* __restrict__ wl2, const float* __restrict__ wr2,
    const float* __restrict__ wl3, const float* __restrict__ wr3,
    unsigned short* __restrict__ bt1, unsigned short* __restrict__ bt2,
    unsigned short* __restrict__ bt3,
    const float* __restrict__ b1, const float* __restrict__ g1, const float* __restrict__ be1,
    const float* __restrict__ m1, const float* __restrict__ v1,
    const float* __restrict__ b2, const float* __restrict__ g2, const float* __restrict__ be2,
    const float* __restrict__ m2, const float* __restrict__ v2,
    const float* __restrict__ b3,
    float* __restrict__ sc1, float* __restrict__ sh1,
    float* __restrict__ sc2, float* __restrict__ sh2,
    float* __restrict__ sc3, float* __restrict__ sh3,
    const int* __restrict__ dstI, int* __restrict__ deg) {
    const int b = blockIdx.x, tid = threadIdx.x;
    if (b < 5000) {                       // x cast
        int i = b * 256 + tid;
        float4 f = ((const float4*)x)[i];
        ushort4 o;
        o.x = f2bf(f.x); o.y = f2bf(f.y); o.z = f2bf(f.z); o.w = f2bf(f.w);
        ((ushort4*)xb)[i] = o;
        return;
    }
    if (b >= 6281) {                      // edge degree count
        int e = (b - 6281) * 256 + tid;
        if (e < NEDGE) atomicAdd(&deg[dstI[e]], 1);
        return;
    }
    if (b == 6280) {                      // scale/shift
        for (int t = tid; t < 512; t += 256) {
            float s1 = g1[t] * rsqrtf(v1[t] + 1e-5f);
            sc1[t] = s1; sh1[t] = (b1[t] - m1[t]) * s1 + be1[t];
            float s2 = g2[t] * rsqrtf(v2[t] + 1e-5f);
            sc2[t] = s2; sh2[t] = (b2[t] - m2[t]) * s2 + be2[t];
        }
        if (tid < 256) { sc3[tid] = 1.0f; sh3[tid] = b3[tid]; }
        return;
    }
    __shared__ float t[32][33];
    int tj = b - 5000;
    const float* srcp; unsigned short* dstp; int C, koff, ntilesN;
    if (tj < 1024) {
        int job = tj >> 8; int tile = tj & 255; C = 512; ntilesN = 16;
        srcp = (job == 0) ? wl1 : (job == 1) ? wr1 : (job == 2) ? wl2 : wr2;
        dstp = (job < 2) ? bt1 : bt2; koff = (job & 1) * 512;
        tj = tile;
    } else {
        int jj = tj - 1024; int job = jj >> 7; int tile = jj & 127; C = 256; ntilesN = 8;
        srcp = (job == 0) ? wl3 : wr3; dstp = bt3; koff = job * 512;
        tj = tile;
    }
    int k0 = (tj / ntilesN) * 32, c0 = (tj % ntilesN) * 32;
    int tx = tid & 31, ty = tid >> 5;
#pragma unroll
    for (int q = 0; q < 4; q++)
        t[ty + 8 * q][tx] = srcp[(long)(k0 + ty + 8 * q) * C + c0 + tx];
    __syncthreads();
#pragma unroll
    for (int q = 0; q < 4; q++)
        dstp[(long)(c0 + ty + 8 * q) * 1024 + koff + k0 + tx] = f2bf(t[tx][ty + 8 * q]);
}

// ---------------- aggregation: XCD-column-affine, oct-wave edge-parallel ----------------
// Block b: XCD (b&7) owns 64 cols [64X, 64X+64) -> per-XCD slice 10000*64*2B = 1.28MB (L2-resident,
// 16x edge reuse). Each 1/8-wave (8 lanes x 16B) handles one edge: 8 edges per wave-step ->
// 160K dependent csr->gather chains total (half of R8), 1 gather instruction per 8 edges.
__global__ __launch_bounds__(256) void k_agg(const unsigned short* __restrict__ S,
                                             const int* __restrict__ rs, const int* __restrict__ csr,
                                             unsigned short* __restrict__ outb) {
    const int X = blockIdx.x & 7;
    const int wv = (blockIdx.x >> 3) * 4 + (threadIdx.x >> 6);   // 0..1023
    const int lane = threadIdx.x & 63;
    const int oct = lane >> 3;                                   // 0..7: edge slot
    const int cbase = X * 64 + (lane & 7) * 8;                   // 8 cols (16B) per lane
    for (int n = wv; n < NNODE; n += 1024) {
        const int s = rs[n], e = rs[n + 1];
        float a0 = 0.f, a1 = 0.f, a2 = 0.f, a3 = 0.f, a4 = 0.f, a5 = 0.f, a6 = 0.f, a7 = 0.f;
        for (int i = s; i < e; i += 8) {
            const int j = i + oct;
            if (j < e) {
                const int r = csr[j];
                uint4 u = *(const uint4*)(S + (long)r * 512 + cbase);
                a0 += bf2f((unsigned short)(u.x & 0xffffu)); a1 += bf2f((unsigned short)(u.x >> 16));
                a2 += bf2f((unsigned short)(u.y & 0xffffu)); a3 += bf2f((unsigned short)(u.y >> 16));
                a4 += bf2f((unsigned short)(u.z & 0xffffu)); a5 += bf2f((unsigned short)(u.z >> 16));
                a6 += bf2f((unsigned short)(u.w & 0xffffu)); a7 += bf2f((unsigned short)(u.w >> 16));
            }
        }
#pragma unroll
        for (int d = 8; d < 64; d <<= 1) {
            a0 += __shfl_xor(a0, d, 64); a1 += __shfl_xor(a1, d, 64);
            a2 += __shfl_xor(a2, d, 64); a3 += __shfl_xor(a3, d, 64);
            a4 += __shfl_xor(a4, d, 64); a5 += __shfl_xor(a5, d, 64);
            a6 += __shfl_xor(a6, d, 64); a7 += __shfl_xor(a7, d, 64);
        }
        if (oct == 0) {
            const int cnt = e - s;
            const float inv = 1.f / (float)(cnt > 1 ? cnt : 1);
            uint4 o;
            o.x = (unsigned)f2bf(a0 * inv) | ((unsigned)f2bf(a1 * inv) << 16);
            o.y = (unsigned)f2bf(a2 * inv) | ((unsigned)f2bf(a3 * inv) << 16);
            o.z = (unsigned)f2bf(a4 * inv) | ((unsigned)f2bf(a5 * inv) << 16);
            o.w = (unsigned)f2bf(a6 * inv) | ((unsigned)f2bf(a7 * inv) << 16);
            *(uint4*)(outb + (long)n * 512 + cbase) = o;
        }
    }
}

// ---------------- GEMM: 128x128 tile, 4x4 frags/wave, LDS dbuf (1 barrier/iter), XCD swizzle ----------------
// C[M x NOUT] = [Agg|Self][M x 1024] @ Bt[NOUT x 1024]^T, BK=64.
// MODE 0: relu(dot*sc+sh) -> bf16 stride 512 ; MODE 1: dot*sc+sh -> fp32 stride NOUT.
template <int MODE, int NOUT>
__global__ __launch_bounds__(256, 2) void k_gemm(const unsigned short* __restrict__ Agg,
                                                 const unsigned short* __restrict__ Self,
                                                 const unsigned short* __restrict__ Bt,
                                                 const float* __restrict__ sc, const float* __restrict__ sh,
                                                 unsigned short* __restrict__ hout, float* __restrict__ fout,
                                                 int M) {
    constexpr int NT = NOUT / 128;          // n-tiles: 4 or 2
    constexpr int QSH = (NT == 4) ? 5 : 4;  // 3 + log2(NT)
    const int b = blockIdx.x;
    const int X = b & 7;
    const int q = (b >> 3) & (NT - 1);
    const int g = b >> QSH;
    const int m0 = (g * 8 + X) * 128;
    if (m0 >= M) return;
    const int n0 = q * 128;

    __shared__ __align__(16) short As[2][128 * 64];   // 32 KB
    __shared__ __align__(16) short Bs[2][128 * 64];   // 32 KB
    const int tid = threadIdx.x;
    const int w = tid >> 6, lane = tid & 63;
    const int wm = (w >> 1) * 64, wn = (w & 1) * 64;
    const int fr = lane & 15, fq = lane >> 4, sw = fr & 7;
    const int srow = w * 8 + (lane >> 3);
    const int scol = (((lane & 7) ^ (lane >> 3)) * 8);
    const int ldsOff = w * 8 * 64;

    f32x4 acc[4][4];
#pragma unroll
    for (int i = 0; i < 4; i++)
#pragma unroll
        for (int j = 0; j < 4; j++)
#pragma unroll
            for (int r = 0; r < 4; r++) acc[i][j][r] = 0.f;

    auto issue = [&](int t, int buf) {
        const short* abase = (const short*)((t < 8) ? Agg : Self);
        const int kk = (t & 7) * 64;
        const int k0 = t * 64;
#pragma unroll
        for (int cch = 0; cch < 4; cch++) {
            __builtin_amdgcn_global_load_lds(
                (const __attribute__((address_space(1))) void*)(abase + (long)(m0 + cch * 32 + srow) * 512 + kk + scol),
                (__attribute__((address_space(3))) void*)(&As[buf][ldsOff + cch * 32 * 64]), 16, 0, 0);
            __builtin_amdgcn_global_load_lds(
                (const __attribute__((address_space(1))) void*)((const short*)Bt + (long)(n0 + cch * 32 + srow) * 1024 + k0 + scol),
                (__attribute__((address_space(3))) void*)(&Bs[buf][ldsOff + cch * 32 * 64]), 16, 0, 0);
        }
    };

    issue(0, 0);
#pragma unroll
    for (int t = 0; t < 16; t++) {
        const int cur = t & 1;
        __syncthreads();
        if (t < 15) issue(t + 1, cur ^ 1);
#pragma unroll
        for (int ks = 0; ks < 2; ks++) {
            frag8 af[4], bf[4];
#pragma unroll
            for (int i = 0; i < 4; i++)
                af[i] = *(const frag8*)(&As[cur][(wm + i * 16 + fr) * 64 + (((ks * 4 + fq) ^ sw) * 8)]);
#pragma unroll
            for (int j = 0; j < 4; j++)
                bf[j] = *(const frag8*)(&Bs[cur][(wn + j * 16 + fr) * 64 + (((ks * 4 + fq) ^ sw) * 8)]);
#pragma unroll
            for (int i = 0; i < 4; i++)
#pragma unroll
                for (int j = 0; j < 4; j++)
                    acc[i][j] = __builtin_amdgcn_mfma_f32_16x16x32_bf16(af[i], bf[j], acc[i][j], 0, 0, 0);
        }
    }

    float scj[4], shj[4];
#pragma unroll
    for (int j = 0; j < 4; j++) {
        int col = n0 + wn + j * 16 + fr;
        scj[j] = sc[col]; shj[j] = sh[col];
    }
#pragma unroll
    for (int i = 0; i < 4; i++) {
        int rowb = m0 + wm + i * 16 + fq * 4;
#pragma unroll
        for (int j = 0; j < 4; j++) {
            int col = n0 + wn + j * 16 + fr;
#pragma unroll
            for (int r = 0; r < 4; r++) {
                int row = rowb + r;
                if (row < M) {
                    float y = acc[i][j][r] * scj[j] + shj[j];
                    if constexpr (MODE == 0) {
                        y = fmaxf(y, 0.f);
                        hout[(long)row * 512 + col] = f2bf(y);
                    } else {
                        fout[(long)row * NOUT + col] = y;
                    }
                }
            }
        }
    }
}

extern "C" void kernel_launch(void* const* d_in, const int* in_sizes, int n_in,
                              void* d_out, int out_size, void* d_ws, size_t ws_size,
                              hipStream_t stream) {
    const float* x    = (const float*)d_in[0];
    const int*   ei   = (const int*)d_in[1];
    const float* w_l1 = (const float*)d_in[2];
    const float* b1   = (const float*)d_in[3];
    const float* w_r1 = (const float*)d_in[4];
    const float* g1   = (const float*)d_in[5];
    const float* be1  = (const float*)d_in[6];
    const float* m1   = (const float*)d_in[7];
    const float* v1   = (const float*)d_in[8];
    const float* w_l2 = (const float*)d_in[9];
    const float* b2   = (const float*)d_in[10];
    const float* w_r2 = (const float*)d_in[11];
    const float* g2   = (const float*)d_in[12];
    const float* be2  = (const float*)d_in[13];
    const float* m2   = (const float*)d_in[14];
    const float* v2   = (const float*)d_in[15];
    const float* w_l3 = (const float*)d_in[16];
    const float* b3   = (const float*)d_in[17];
    const float* w_r3 = (const float*)d_in[18];
    float* out = (float*)d_out;

    const int N = NNODE, E = NEDGE;
    const int* srcI = ei;
    const int* dstI = ei + E;

    char* w = (char*)d_ws;
    auto alloc = [&](size_t bytes) { void* p = (void*)w; w += (bytes + 255) & ~(size_t)255; return p; };
    int* deg = (int*)alloc((size_t)N * 4);
    int* rs  = (int*)alloc((size_t)(N + 1) * 4);
    int* cur = (int*)alloc((size_t)N * 4);
    int* csr = (int*)alloc((size_t)E * 4);
    unsigned short* xb   = (unsigned short*)alloc((size_t)N * 512 * 2);
    unsigned short* bt1  = (unsigned short*)alloc((size_t)512 * 1024 * 2);
    unsigned short* bt2  = (unsigned short*)alloc((size_t)512 * 1024 * 2);
    unsigned short* bt3  = (unsigned short*)alloc((size_t)256 * 1024 * 2);
    float* sc1 = (float*)alloc(512 * 4); float* sh1 = (float*)alloc(512 * 4);
    float* sc2 = (float*)alloc(512 * 4); float* sh2 = (float*)alloc(512 * 4);
    float* sc3 = (float*)alloc(256 * 4); float* sh3 = (float*)alloc(256 * 4);
    unsigned short* agg_a = (unsigned short*)alloc((size_t)N * 512 * 2);
    unsigned short* h1    = (unsigned short*)alloc((size_t)N * 512 * 2);
    unsigned short* h2    = (unsigned short*)alloc((size_t)N * 512 * 2);
    (void)alloc(256 * 1024);  // DMA over-read slack for last M-tile

    hipMemsetAsync(deg, 0, (size_t)N * 4, stream);
    k_prep<<<6906, 256, 0, stream>>>(x, xb, w_l1, w_r1, w_l2, w_r2, w_l3, w_r3,
                                     bt1, bt2, bt3,
                                     b1, g1, be1, m1, v1, b2, g2, be2, m2, v2, b3,
                                     sc1, sh1, sc2, sh2, sc3, sh3, dstI, deg);
    k_scan<<<1, 1024, 0, stream>>>(deg, rs, cur, N, E);
    k_fill<<<(E + 255) / 256, 256, 0, stream>>>(srcI, dstI, E, cur, csr);

    // Layer 1
    k_agg<<<2048, 256, 0, stream>>>(xb, rs, csr, agg_a);
    k_gemm<0, 512><<<320, 256, 0, stream>>>(agg_a, xb, bt1, sc1, sh1, h1, nullptr, N);
    // Layer 2
    k_agg<<<2048, 256, 0, stream>>>(h1, rs, csr, agg_a);
    k_gemm<0, 512><<<320, 256, 0, stream>>>(agg_a, h1, bt2, sc2, sh2, h2, nullptr, N);
    // Layer 3
    k_agg<<<2048, 256, 0, stream>>>(h2, rs, csr, agg_a);
    k_gemm<1, 256><<<160, 256, 0, stream>>>(agg_a, h2, bt3, sc3, sh3, nullptr, out, N);
}

// Round 11
// 258.510 us; speedup vs baseline: 1.1273x; 1.0947x over previous
//
#include <hip/hip_runtime.h>

#define NNODE 10000
#define NEDGE 160000

using frag8 = __attribute__((ext_vector_type(8))) short;
using f32x4 = __attribute__((ext_vector_type(4))) float;

__device__ __forceinline__ unsigned short f2bf(float f) {
    union { float f; unsigned u; } v; v.f = f;
    unsigned r = (v.u + 0x7fffu + ((v.u >> 16) & 1u)) >> 16;
    return (unsigned short)r;
}
__device__ __forceinline__ float bf2f(unsigned short s) {
    union { unsigned u; float f; } v; v.u = ((unsigned)s) << 16; return v.f;
}

// ---------------- scan ----------------
__global__ __launch_bounds__(1024) void k_scan(const int* __restrict__ deg,
                                               int* __restrict__ rs,
                                               int* __restrict__ cur, int n, int total) {
    const int tid = threadIdx.x;
    const int CH = 10;
    const int base = tid * CH;
    int vals[CH];
    int tsum = 0;
#pragma unroll
    for (int j = 0; j < CH; j++) {
        int v = (base + j < n) ? deg[base + j] : 0;
        vals[j] = v; tsum += v;
    }
    const int lane = tid & 63, wid = tid >> 6;
    int x = tsum;
#pragma unroll
    for (int d = 1; d < 64; d <<= 1) {
        int y = __shfl_up(x, d, 64);
        if (lane >= d) x += y;
    }
    __shared__ int wt[16];
    if (lane == 63) wt[wid] = x;
    __syncthreads();
    if (tid == 0) {
        int c = 0;
#pragma unroll
        for (int k = 0; k < 16; k++) { int t = wt[k]; wt[k] = c; c += t; }
    }
    __syncthreads();
    int run = wt[wid] + x - tsum;
#pragma unroll
    for (int j = 0; j < CH; j++) {
        if (base + j < n) { rs[base + j] = run; cur[base + j] = run; }
        run += vals[j];
    }
    if (tid == 0) rs[n] = total;
}

__global__ void k_fill(const int* __restrict__ src, const int* __restrict__ dst,
                       int E, int* __restrict__ cur, int* __restrict__ csr) {
    int e = blockIdx.x * 256 + threadIdx.x;
    if (e < E) {
        int p = atomicAdd(&cur[dst[e]], 1);
        csr[p] = src[e];
    }
}

// ---------------- fused prep: x-cast + weight transposes + scale/shift + edge count ----------------
__global__ __launch_bounds__(256) void k_prep(
    const float* __restrict__ x, unsigned short* __restrict__ xb,
    const float* __restrict__ wl1, const float* __restrict__ wr1,
    const float* __restrict__ wl2, const float* __restrict__ wr2,
    const float* __restrict__ wl3, const float* __restrict__ wr3,
    unsigned short* __restrict__ bt1, unsigned short* __restrict__ bt2,
    unsigned short* __restrict__ bt3,
    const float* __restrict__ b1, const float* __restrict__ g1, const float* __restrict__ be1,
    const float* __restrict__ m1, const float* __restrict__ v1,
    const float* __restrict__ b2, const float* __restrict__ g2, const float* __restrict__ be2,
    const float* __restrict__ m2, const float* __restrict__ v2,
    const float* __restrict__ b3,
    float* __restrict__ sc1, float* __restrict__ sh1,
    float* __restrict__ sc2, float* __restrict__ sh2,
    float* __restrict__ sc3, float* __restrict__ sh3,
    const int* __restrict__ dstI, int* __restrict__ deg) {
    const int b = blockIdx.x, tid = threadIdx.x;
    if (b < 5000) {                       // x cast
        int i = b * 256 + tid;
        float4 f = ((const float4*)x)[i];
        ushort4 o;
        o.x = f2bf(f.x); o.y = f2bf(f.y); o.z = f2bf(f.z); o.w = f2bf(f.w);
        ((ushort4*)xb)[i] = o;
        return;
    }
    if (b >= 6281) {                      // edge degree count
        int e = (b - 6281) * 256 + tid;
        if (e < NEDGE) atomicAdd(&deg[dstI[e]], 1);
        return;
    }
    if (b == 6280) {                      // scale/shift
        for (int t = tid; t < 512; t += 256) {
            float s1 = g1[t] * rsqrtf(v1[t] + 1e-5f);
            sc1[t] = s1; sh1[t] = (b1[t] - m1[t]) * s1 + be1[t];
            float s2 = g2[t] * rsqrtf(v2[t] + 1e-5f);
            sc2[t] = s2; sh2[t] = (b2[t] - m2[t]) * s2 + be2[t];
        }
        if (tid < 256) { sc3[tid] = 1.0f; sh3[tid] = b3[tid]; }
        return;
    }
    __shared__ float t[32][33];
    int tj = b - 5000;
    const float* srcp; unsigned short* dstp; int C, koff, ntilesN;
    if (tj < 1024) {
        int job = tj >> 8; int tile = tj & 255; C = 512; ntilesN = 16;
        srcp = (job == 0) ? wl1 : (job == 1) ? wr1 : (job == 2) ? wl2 : wr2;
        dstp = (job < 2) ? bt1 : bt2; koff = (job & 1) * 512;
        tj = tile;
    } else {
        int jj = tj - 1024; int job = jj >> 7; int tile = jj & 127; C = 256; ntilesN = 8;
        srcp = (job == 0) ? wl3 : wr3; dstp = bt3; koff = job * 512;
        tj = tile;
    }
    int k0 = (tj / ntilesN) * 32, c0 = (tj % ntilesN) * 32;
    int tx = tid & 31, ty = tid >> 5;
#pragma unroll
    for (int q = 0; q < 4; q++)
        t[ty + 8 * q][tx] = srcp[(long)(k0 + ty + 8 * q) * C + c0 + tx];
    __syncthreads();
#pragma unroll
    for (int q = 0; q < 4; q++)
        dstp[(long)(c0 + ty + 8 * q) * 1024 + koff + k0 + tx] = f2bf(t[tx][ty + 8 * q]);
}

// ---------------- aggregation: 1 pass, uint4 (full 512-col row per gather) ----------------
// One wave per node. Lane covers 16B = 8 cols; 64 lanes = 512 cols. Each edge processed ONCE:
// half the csr-chain count of the 2-pass version, same gather bytes, same 16B/lane coalescing.
__global__ __launch_bounds__(64) void k_agg(const unsigned short* __restrict__ S,
                                            const int* __restrict__ rs, const int* __restrict__ csr,
                                            unsigned short* __restrict__ outb) {
    const int n = blockIdx.x;
    const int c = threadIdx.x * 8;
    const int s = rs[n], e = rs[n + 1];
    float a0 = 0.f, a1 = 0.f, a2 = 0.f, a3 = 0.f, a4 = 0.f, a5 = 0.f, a6 = 0.f, a7 = 0.f;
    int i = s;
    for (; i + 4 <= e; i += 4) {
        int r0 = csr[i], r1 = csr[i + 1], r2 = csr[i + 2], r3 = csr[i + 3];
        uint4 u0 = *(const uint4*)(S + (long)r0 * 512 + c);
        uint4 u1 = *(const uint4*)(S + (long)r1 * 512 + c);
        uint4 u2 = *(const uint4*)(S + (long)r2 * 512 + c);
        uint4 u3 = *(const uint4*)(S + (long)r3 * 512 + c);
        a0 += bf2f((unsigned short)(u0.x & 0xffffu)) + bf2f((unsigned short)(u1.x & 0xffffu))
            + bf2f((unsigned short)(u2.x & 0xffffu)) + bf2f((unsigned short)(u3.x & 0xffffu));
        a1 += bf2f((unsigned short)(u0.x >> 16)) + bf2f((unsigned short)(u1.x >> 16))
            + bf2f((unsigned short)(u2.x >> 16)) + bf2f((unsigned short)(u3.x >> 16));
        a2 += bf2f((unsigned short)(u0.y & 0xffffu)) + bf2f((unsigned short)(u1.y & 0xffffu))
            + bf2f((unsigned short)(u2.y & 0xffffu)) + bf2f((unsigned short)(u3.y & 0xffffu));
        a3 += bf2f((unsigned short)(u0.y >> 16)) + bf2f((unsigned short)(u1.y >> 16))
            + bf2f((unsigned short)(u2.y >> 16)) + bf2f((unsigned short)(u3.y >> 16));
        a4 += bf2f((unsigned short)(u0.z & 0xffffu)) + bf2f((unsigned short)(u1.z & 0xffffu))
            + bf2f((unsigned short)(u2.z & 0xffffu)) + bf2f((unsigned short)(u3.z & 0xffffu));
        a5 += bf2f((unsigned short)(u0.z >> 16)) + bf2f((unsigned short)(u1.z >> 16))
            + bf2f((unsigned short)(u2.z >> 16)) + bf2f((unsigned short)(u3.z >> 16));
        a6 += bf2f((unsigned short)(u0.w & 0xffffu)) + bf2f((unsigned short)(u1.w & 0xffffu))
            + bf2f((unsigned short)(u2.w & 0xffffu)) + bf2f((unsigned short)(u3.w & 0xffffu));
        a7 += bf2f((unsigned short)(u0.w >> 16)) + bf2f((unsigned short)(u1.w >> 16))
            + bf2f((unsigned short)(u2.w >> 16)) + bf2f((unsigned short)(u3.w >> 16));
    }
    for (; i < e; i++) {
        uint4 u = *(const uint4*)(S + (long)csr[i] * 512 + c);
        a0 += bf2f((unsigned short)(u.x & 0xffffu)); a1 += bf2f((unsigned short)(u.x >> 16));
        a2 += bf2f((unsigned short)(u.y & 0xffffu)); a3 += bf2f((unsigned short)(u.y >> 16));
        a4 += bf2f((unsigned short)(u.z & 0xffffu)); a5 += bf2f((unsigned short)(u.z >> 16));
        a6 += bf2f((unsigned short)(u.w & 0xffffu)); a7 += bf2f((unsigned short)(u.w >> 16));
    }
    const int cnt = e - s;
    const float inv = 1.f / (float)(cnt > 1 ? cnt : 1);
    uint4 o;
    o.x = (unsigned)f2bf(a0 * inv) | ((unsigned)f2bf(a1 * inv) << 16);
    o.y = (unsigned)f2bf(a2 * inv) | ((unsigned)f2bf(a3 * inv) << 16);
    o.z = (unsigned)f2bf(a4 * inv) | ((unsigned)f2bf(a5 * inv) << 16);
    o.w = (unsigned)f2bf(a6 * inv) | ((unsigned)f2bf(a7 * inv) << 16);
    *(uint4*)(outb + (long)n * 512 + c) = o;
}

// ---------------- GEMM: 128x128 tile, 4x4 frags/wave, LDS dbuf (1 barrier/iter), XCD swizzle ----------------
// C[M x NOUT] = [Agg|Self][M x 1024] @ Bt[NOUT x 1024]^T, BK=64.
// MODE 0: relu(dot*sc+sh) -> bf16 stride 512 ; MODE 1: dot*sc+sh -> fp32 stride NOUT.
template <int MODE, int NOUT>
__global__ __launch_bounds__(256, 2) void k_gemm(const unsigned short* __restrict__ Agg,
                                                 const unsigned short* __restrict__ Self,
                                                 const unsigned short* __restrict__ Bt,
                                                 const float* __restrict__ sc, const float* __restrict__ sh,
                                                 unsigned short* __restrict__ hout, float* __restrict__ fout,
                                                 int M) {
    constexpr int NT = NOUT / 128;          // n-tiles: 4 or 2
    constexpr int QSH = (NT == 4) ? 5 : 4;  // 3 + log2(NT)
    const int b = blockIdx.x;
    const int X = b & 7;
    const int q = (b >> 3) & (NT - 1);
    const int g = b >> QSH;
    const int m0 = (g * 8 + X) * 128;
    if (m0 >= M) return;
    const int n0 = q * 128;

    __shared__ __align__(16) short As[2][128 * 64];   // 32 KB
    __shared__ __align__(16) short Bs[2][128 * 64];   // 32 KB
    const int tid = threadIdx.x;
    const int w = tid >> 6, lane = tid & 63;
    const int wm = (w >> 1) * 64, wn = (w & 1) * 64;
    const int fr = lane & 15, fq = lane >> 4, sw = fr & 7;
    const int srow = w * 8 + (lane >> 3);
    const int scol = (((lane & 7) ^ (lane >> 3)) * 8);
    const int ldsOff = w * 8 * 64;

    f32x4 acc[4][4];
#pragma unroll
    for (int i = 0; i < 4; i++)
#pragma unroll
        for (int j = 0; j < 4; j++)
#pragma unroll
            for (int r = 0; r < 4; r++) acc[i][j][r] = 0.f;

    auto issue = [&](int t, int buf) {
        const short* abase = (const short*)((t < 8) ? Agg : Self);
        const int kk = (t & 7) * 64;
        const int k0 = t * 64;
#pragma unroll
        for (int cch = 0; cch < 4; cch++) {
            __builtin_amdgcn_global_load_lds(
                (const __attribute__((address_space(1))) void*)(abase + (long)(m0 + cch * 32 + srow) * 512 + kk + scol),
                (__attribute__((address_space(3))) void*)(&As[buf][ldsOff + cch * 32 * 64]), 16, 0, 0);
            __builtin_amdgcn_global_load_lds(
                (const __attribute__((address_space(1))) void*)((const short*)Bt + (long)(n0 + cch * 32 + srow) * 1024 + k0 + scol),
                (__attribute__((address_space(3))) void*)(&Bs[buf][ldsOff + cch * 32 * 64]), 16, 0, 0);
        }
    };

    issue(0, 0);
#pragma unroll
    for (int t = 0; t < 16; t++) {
        const int cur = t & 1;
        __syncthreads();
        if (t < 15) issue(t + 1, cur ^ 1);
#pragma unroll
        for (int ks = 0; ks < 2; ks++) {
            frag8 af[4], bf[4];
#pragma unroll
            for (int i = 0; i < 4; i++)
                af[i] = *(const frag8*)(&As[cur][(wm + i * 16 + fr) * 64 + (((ks * 4 + fq) ^ sw) * 8)]);
#pragma unroll
            for (int j = 0; j < 4; j++)
                bf[j] = *(const frag8*)(&Bs[cur][(wn + j * 16 + fr) * 64 + (((ks * 4 + fq) ^ sw) * 8)]);
#pragma unroll
            for (int i = 0; i < 4; i++)
#pragma unroll
                for (int j = 0; j < 4; j++)
                    acc[i][j] = __builtin_amdgcn_mfma_f32_16x16x32_bf16(af[i], bf[j], acc[i][j], 0, 0, 0);
        }
    }

    float scj[4], shj[4];
#pragma unroll
    for (int j = 0; j < 4; j++) {
        int col = n0 + wn + j * 16 + fr;
        scj[j] = sc[col]; shj[j] = sh[col];
    }
#pragma unroll
    for (int i = 0; i < 4; i++) {
        int rowb = m0 + wm + i * 16 + fq * 4;
#pragma unroll
        for (int j = 0; j < 4; j++) {
            int col = n0 + wn + j * 16 + fr;
#pragma unroll
            for (int r = 0; r < 4; r++) {
                int row = rowb + r;
                if (row < M) {
                    float y = acc[i][j][r] * scj[j] + shj[j];
                    if constexpr (MODE == 0) {
                        y = fmaxf(y, 0.f);
                        hout[(long)row * 512 + col] = f2bf(y);
                    } else {
                        fout[(long)row * NOUT + col] = y;
                    }
                }
            }
        }
    }
}

extern "C" void kernel_launch(void* const* d_in, const int* in_sizes, int n_in,
                              void* d_out, int out_size, void* d_ws, size_t ws_size,
                              hipStream_t stream) {
    const float* x    = (const float*)d_in[0];
    const int*   ei   = (const int*)d_in[1];
    const float* w_l1 = (const float*)d_in[2];
    const float* b1   = (const float*)d_in[3];
    const float* w_r1 = (const float*)d_in[4];
    const float* g1   = (const float*)d_in[5];
    const float* be1  = (const float*)d_in[6];
    const float* m1   = (const float*)d_in[7];
    const float* v1   = (const float*)d_in[8];
    const float* w_l2 = (const float*)d_in[9];
    const float* b2   = (const float*)d_in[10];
    const float* w_r2 = (const float*)d_in[11];
    const float* g2   = (const float*)d_in[12];
    const float* be2  = (const float*)d_in[13];
    const float* m2   = (const float*)d_in[14];
    const float* v2   = (const float*)d_in[15];
    const float* w_l3 = (const float*)d_in[16];
    const float* b3   = (const float*)d_in[17];
    const float* w_r3 = (const float*)d_in[18];
    float* out = (float*)d_out;

    const int N = NNODE, E = NEDGE;
    const int* srcI = ei;
    const int* dstI = ei + E;

    char* w = (char*)d_ws;
    auto alloc = [&](size_t bytes) { void* p = (void*)w; w += (bytes + 255) & ~(size_t)255; return p; };
    int* deg = (int*)alloc((size_t)N * 4);
    int* rs  = (int*)alloc((size_t)(N + 1) * 4);
    int* cur = (int*)alloc((size_t)N * 4);
    int* csr = (int*)alloc((size_t)E * 4);
    unsigned short* xb   = (unsigned short*)alloc((size_t)N * 512 * 2);
    unsigned short* bt1  = (unsigned short*)alloc((size_t)512 * 1024 * 2);
    unsigned short* bt2  = (unsigned short*)alloc((size_t)512 * 1024 * 2);
    unsigned short* bt3  = (unsigned short*)alloc((size_t)256 * 1024 * 2);
    float* sc1 = (float*)alloc(512 * 4); float* sh1 = (float*)alloc(512 * 4);
    float* sc2 = (float*)alloc(512 * 4); float* sh2 = (float*)alloc(512 * 4);
    float* sc3 = (float*)alloc(256 * 4); float* sh3 = (float*)alloc(256 * 4);
    unsigned short* agg_a = (unsigned short*)alloc((size_t)N * 512 * 2);
    unsigned short* h1    = (unsigned short*)alloc((size_t)N * 512 * 2);
    unsigned short* h2    = (unsigned short*)alloc((size_t)N * 512 * 2);
    (void)alloc(256 * 1024);  // DMA over-read slack for last M-tile

    hipMemsetAsync(deg, 0, (size_t)N * 4, stream);
    k_prep<<<6906, 256, 0, stream>>>(x, xb, w_l1, w_r1, w_l2, w_r2, w_l3, w_r3,
                                     bt1, bt2, bt3,
                                     b1, g1, be1, m1, v1, b2, g2, be2, m2, v2, b3,
                                     sc1, sh1, sc2, sh2, sc3, sh3, dstI, deg);
    k_scan<<<1, 1024, 0, stream>>>(deg, rs, cur, N, E);
    k_fill<<<(E + 255) / 256, 256, 0, stream>>>(srcI, dstI, E, cur, csr);

    // Layer 1
    k_agg<<<N, 64, 0, stream>>>(xb, rs, csr, agg_a);
    k_gemm<0, 512><<<320, 256, 0, stream>>>(agg_a, xb, bt1, sc1, sh1, h1, nullptr, N);
    // Layer 2
    k_agg<<<N, 64, 0, stream>>>(h1, rs, csr, agg_a);
    k_gemm<0, 512><<<320, 256, 0, stream>>>(agg_a, h1, bt2, sc2, sh2, h2, nullptr, N);
    // Layer 3
    k_agg<<<N, 64, 0, stream>>>(h2, rs, csr, agg_a);
    k_gemm<1, 256><<<160, 256, 0, stream>>>(agg_a, h2, bt3, sc3, sh3, nullptr, out, N);
}

// Round 12
// 252.837 us; speedup vs baseline: 1.1526x; 1.0224x over previous
//
#include <hip/hip_runtime.h>

#define NNODE 10000
#define NEDGE 160000

using frag8 = __attribute__((ext_vector_type(8))) short;
using f32x4 = __attribute__((ext_vector_type(4))) float;

__device__ __forceinline__ unsigned short f2bf(float f) {
    union { float f; unsigned u; } v; v.f = f;
    unsigned r = (v.u + 0x7fffu + ((v.u >> 16) & 1u)) >> 16;
    return (unsigned short)r;
}
__device__ __forceinline__ float bf2f(unsigned short s) {
    union { unsigned u; float f; } v; v.u = ((unsigned)s) << 16; return v.f;
}

// ---------------- scan ----------------
__global__ __launch_bounds__(1024) void k_scan(const int* __restrict__ deg,
                                               int* __restrict__ rs,
                                               int* __restrict__ cur, int n, int total) {
    const int tid = threadIdx.x;
    const int CH = 10;
    const int base = tid * CH;
    int vals[CH];
    int tsum = 0;
#pragma unroll
    for (int j = 0; j < CH; j++) {
        int v = (base + j < n) ? deg[base + j] : 0;
        vals[j] = v; tsum += v;
    }
    const int lane = tid & 63, wid = tid >> 6;
    int x = tsum;
#pragma unroll
    for (int d = 1; d < 64; d <<= 1) {
        int y = __shfl_up(x, d, 64);
        if (lane >= d) x += y;
    }
    __shared__ int wt[16];
    if (lane == 63) wt[wid] = x;
    __syncthreads();
    if (tid == 0) {
        int c = 0;
#pragma unroll
        for (int k = 0; k < 16; k++) { int t = wt[k]; wt[k] = c; c += t; }
    }
    __syncthreads();
    int run = wt[wid] + x - tsum;
#pragma unroll
    for (int j = 0; j < CH; j++) {
        if (base + j < n) { rs[base + j] = run; cur[base + j] = run; }
        run += vals[j];
    }
    if (tid == 0) rs[n] = total;
}

__global__ void k_fill(const int* __restrict__ src, const int* __restrict__ dst,
                       int E, int* __restrict__ cur, int* __restrict__ csr) {
    int e = blockIdx.x * 256 + threadIdx.x;
    if (e < E) {
        int p = atomicAdd(&cur[dst[e]], 1);
        csr[p] = src[e];
    }
}

// ---------------- fused prep: x-cast + weight transposes + scale/shift + edge count ----------------
__global__ __launch_bounds__(256) void k_prep(
    const float* __restrict__ x, unsigned short* __restrict__ xb,
    const float* __restrict__ wl1, const float* __restrict__ wr1,
    const float* __restrict__ wl2, const float* __restrict__ wr2,
    const float* __restrict__ wl3, const float* __restrict__ wr3,
    unsigned short* __restrict__ bt1, unsigned short* __restrict__ bt2,
    unsigned short* __restrict__ bt3,
    const float* __restrict__ b1, const float* __restrict__ g1, const float* __restrict__ be1,
    const float* __restrict__ m1, const float* __restrict__ v1,
    const float* __restrict__ b2, const float* __restrict__ g2, const float* __restrict__ be2,
    const float* __restrict__ m2, const float* __restrict__ v2,
    const float* __restrict__ b3,
    float* __restrict__ sc1, float* __restrict__ sh1,
    float* __restrict__ sc2, float* __restrict__ sh2,
    float* __restrict__ sc3, float* __restrict__ sh3,
    const int* __restrict__ dstI, int* __restrict__ deg) {
    const int b = blockIdx.x, tid = threadIdx.x;
    if (b < 5000) {                       // x cast
        int i = b * 256 + tid;
        float4 f = ((const float4*)x)[i];
        ushort4 o;
        o.x = f2bf(f.x); o.y = f2bf(f.y); o.z = f2bf(f.z); o.w = f2bf(f.w);
        ((ushort4*)xb)[i] = o;
        return;
    }
    if (b >= 6281) {                      // edge degree count
        int e = (b - 6281) * 256 + tid;
        if (e < NEDGE) atomicAdd(&deg[dstI[e]], 1);
        return;
    }
    if (b == 6280) {                      // scale/shift
        for (int t = tid; t < 512; t += 256) {
            float s1 = g1[t] * rsqrtf(v1[t] + 1e-5f);
            sc1[t] = s1; sh1[t] = (b1[t] - m1[t]) * s1 + be1[t];
            float s2 = g2[t] * rsqrtf(v2[t] + 1e-5f);
            sc2[t] = s2; sh2[t] = (b2[t] - m2[t]) * s2 + be2[t];
        }
        if (tid < 256) { sc3[tid] = 1.0f; sh3[tid] = b3[tid]; }
        return;
    }
    __shared__ float t[32][33];
    int tj = b - 5000;
    const float* srcp; unsigned short* dstp; int C, koff, ntilesN;
    if (tj < 1024) {
        int job = tj >> 8; int tile = tj & 255; C = 512; ntilesN = 16;
        srcp = (job == 0) ? wl1 : (job == 1) ? wr1 : (job == 2) ? wl2 : wr2;
        dstp = (job < 2) ? bt1 : bt2; koff = (job & 1) * 512;
        tj = tile;
    } else {
        int jj = tj - 1024; int job = jj >> 7; int tile = jj & 127; C = 256; ntilesN = 8;
        srcp = (job == 0) ? wl3 : wr3; dstp = bt3; koff = job * 512;
        tj = tile;
    }
    int k0 = (tj / ntilesN) * 32, c0 = (tj % ntilesN) * 32;
    int tx = tid & 31, ty = tid >> 5;
#pragma unroll
    for (int q = 0; q < 4; q++)
        t[ty + 8 * q][tx] = srcp[(long)(k0 + ty + 8 * q) * C + c0 + tx];
    __syncthreads();
#pragma unroll
    for (int q = 0; q < 4; q++)
        dstp[(long)(c0 + ty + 8 * q) * 1024 + koff + k0 + tx] = f2bf(t[tx][ty + 8 * q]);
}

// ---------------- aggregation: 2 column passes (256 cols/pass), uint2 loads [R8 best config] ----------------
__global__ __launch_bounds__(64) void k_agg(const unsigned short* __restrict__ S,
                                            const int* __restrict__ rs, const int* __restrict__ csr,
                                            unsigned short* __restrict__ outb) {
    const int n = blockIdx.x;
    const int c = blockIdx.y * 256 + threadIdx.x * 4;
    const int s = rs[n], e = rs[n + 1];
    float a0 = 0.f, a1 = 0.f, a2 = 0.f, a3 = 0.f;
    int i = s;
    for (; i + 4 <= e; i += 4) {
        int r0 = csr[i], r1 = csr[i + 1], r2 = csr[i + 2], r3 = csr[i + 3];
        uint2 u0 = *(const uint2*)(S + (long)r0 * 512 + c);
        uint2 u1 = *(const uint2*)(S + (long)r1 * 512 + c);
        uint2 u2 = *(const uint2*)(S + (long)r2 * 512 + c);
        uint2 u3 = *(const uint2*)(S + (long)r3 * 512 + c);
        a0 += bf2f((unsigned short)(u0.x & 0xffffu)); a1 += bf2f((unsigned short)(u0.x >> 16));
        a2 += bf2f((unsigned short)(u0.y & 0xffffu)); a3 += bf2f((unsigned short)(u0.y >> 16));
        a0 += bf2f((unsigned short)(u1.x & 0xffffu)); a1 += bf2f((unsigned short)(u1.x >> 16));
        a2 += bf2f((unsigned short)(u1.y & 0xffffu)); a3 += bf2f((unsigned short)(u1.y >> 16));
        a0 += bf2f((unsigned short)(u2.x & 0xffffu)); a1 += bf2f((unsigned short)(u2.x >> 16));
        a2 += bf2f((unsigned short)(u2.y & 0xffffu)); a3 += bf2f((unsigned short)(u2.y >> 16));
        a0 += bf2f((unsigned short)(u3.x & 0xffffu)); a1 += bf2f((unsigned short)(u3.x >> 16));
        a2 += bf2f((unsigned short)(u3.y & 0xffffu)); a3 += bf2f((unsigned short)(u3.y >> 16));
    }
    for (; i < e; i++) {
        uint2 u = *(const uint2*)(S + (long)csr[i] * 512 + c);
        a0 += bf2f((unsigned short)(u.x & 0xffffu)); a1 += bf2f((unsigned short)(u.x >> 16));
        a2 += bf2f((unsigned short)(u.y & 0xffffu)); a3 += bf2f((unsigned short)(u.y >> 16));
    }
    const int cnt = e - s;
    const float inv = 1.f / (float)(cnt > 1 ? cnt : 1);
    uint2 o;
    o.x = (unsigned)f2bf(a0 * inv) | ((unsigned)f2bf(a1 * inv) << 16);
    o.y = (unsigned)f2bf(a2 * inv) | ((unsigned)f2bf(a3 * inv) << 16);
    *(uint2*)(outb + (long)n * 512 + c) = o;
}

// ---------------- GEMM: 128x128 tile, 4x4 frags/wave, LDS dbuf (1 barrier/iter), XCD swizzle ----------------
// C[M x NOUT] = [Agg|Self][M x 1024] @ Bt[NOUT x 1024]^T, BK=64.
// MODE 0: relu(dot*sc+sh) -> bf16 stride 512 ; MODE 1: dot*sc+sh -> fp32 stride NOUT.
template <int MODE, int NOUT>
__global__ __launch_bounds__(256, 2) void k_gemm(const unsigned short* __restrict__ Agg,
                                                 const unsigned short* __restrict__ Self,
                                                 const unsigned short* __restrict__ Bt,
                                                 const float* __restrict__ sc, const float* __restrict__ sh,
                                                 unsigned short* __restrict__ hout, float* __restrict__ fout,
                                                 int M) {
    constexpr int NT = NOUT / 128;          // n-tiles: 4 or 2
    constexpr int QSH = (NT == 4) ? 5 : 4;  // 3 + log2(NT)
    const int b = blockIdx.x;
    const int X = b & 7;
    const int q = (b >> 3) & (NT - 1);
    const int g = b >> QSH;
    const int m0 = (g * 8 + X) * 128;
    if (m0 >= M) return;
    const int n0 = q * 128;

    __shared__ __align__(16) short As[2][128 * 64];   // 32 KB
    __shared__ __align__(16) short Bs[2][128 * 64];   // 32 KB
    const int tid = threadIdx.x;
    const int w = tid >> 6, lane = tid & 63;
    const int wm = (w >> 1) * 64, wn = (w & 1) * 64;
    const int fr = lane & 15, fq = lane >> 4, sw = fr & 7;
    const int srow = w * 8 + (lane >> 3);
    const int scol = (((lane & 7) ^ (lane >> 3)) * 8);
    const int ldsOff = w * 8 * 64;

    f32x4 acc[4][4];
#pragma unroll
    for (int i = 0; i < 4; i++)
#pragma unroll
        for (int j = 0; j < 4; j++)
#pragma unroll
            for (int r = 0; r < 4; r++) acc[i][j][r] = 0.f;

    auto issue = [&](int t, int buf) {
        const short* abase = (const short*)((t < 8) ? Agg : Self);
        const int kk = (t & 7) * 64;
        const int k0 = t * 64;
#pragma unroll
        for (int cch = 0; cch < 4; cch++) {
            __builtin_amdgcn_global_load_lds(
                (const __attribute__((address_space(1))) void*)(abase + (long)(m0 + cch * 32 + srow) * 512 + kk + scol),
                (__attribute__((address_space(3))) void*)(&As[buf][ldsOff + cch * 32 * 64]), 16, 0, 0);
            __builtin_amdgcn_global_load_lds(
                (const __attribute__((address_space(1))) void*)((const short*)Bt + (long)(n0 + cch * 32 + srow) * 1024 + k0 + scol),
                (__attribute__((address_space(3))) void*)(&Bs[buf][ldsOff + cch * 32 * 64]), 16, 0, 0);
        }
    };

    issue(0, 0);
#pragma unroll
    for (int t = 0; t < 16; t++) {
        const int cur = t & 1;
        __syncthreads();
        if (t < 15) issue(t + 1, cur ^ 1);
#pragma unroll
        for (int ks = 0; ks < 2; ks++) {
            frag8 af[4], bf[4];
#pragma unroll
            for (int i = 0; i < 4; i++)
                af[i] = *(const frag8*)(&As[cur][(wm + i * 16 + fr) * 64 + (((ks * 4 + fq) ^ sw) * 8)]);
#pragma unroll
            for (int j = 0; j < 4; j++)
                bf[j] = *(const frag8*)(&Bs[cur][(wn + j * 16 + fr) * 64 + (((ks * 4 + fq) ^ sw) * 8)]);
#pragma unroll
            for (int i = 0; i < 4; i++)
#pragma unroll
                for (int j = 0; j < 4; j++)
                    acc[i][j] = __builtin_amdgcn_mfma_f32_16x16x32_bf16(af[i], bf[j], acc[i][j], 0, 0, 0);
        }
    }

    float scj[4], shj[4];
#pragma unroll
    for (int j = 0; j < 4; j++) {
        int col = n0 + wn + j * 16 + fr;
        scj[j] = sc[col]; shj[j] = sh[col];
    }
    const bool interior = (m0 + 128 <= M);
#pragma unroll
    for (int i = 0; i < 4; i++) {
        int rowb = m0 + wm + i * 16 + fq * 4;
#pragma unroll
        for (int j = 0; j < 4; j++) {
            int col = n0 + wn + j * 16 + fr;
#pragma unroll
            for (int r = 0; r < 4; r++) {
                int row = rowb + r;
                if (interior || row < M) {
                    float y = acc[i][j][r] * scj[j] + shj[j];
                    if constexpr (MODE == 0) {
                        y = fmaxf(y, 0.f);
                        hout[(long)row * 512 + col] = f2bf(y);
                    } else {
                        fout[(long)row * NOUT + col] = y;
                    }
                }
            }
        }
    }
}

extern "C" void kernel_launch(void* const* d_in, const int* in_sizes, int n_in,
                              void* d_out, int out_size, void* d_ws, size_t ws_size,
                              hipStream_t stream) {
    const float* x    = (const float*)d_in[0];
    const int*   ei   = (const int*)d_in[1];
    const float* w_l1 = (const float*)d_in[2];
    const float* b1   = (const float*)d_in[3];
    const float* w_r1 = (const float*)d_in[4];
    const float* g1   = (const float*)d_in[5];
    const float* be1  = (const float*)d_in[6];
    const float* m1   = (const float*)d_in[7];
    const float* v1   = (const float*)d_in[8];
    const float* w_l2 = (const float*)d_in[9];
    const float* b2   = (const float*)d_in[10];
    const float* w_r2 = (const float*)d_in[11];
    const float* g2   = (const float*)d_in[12];
    const float* be2  = (const float*)d_in[13];
    const float* m2   = (const float*)d_in[14];
    const float* v2   = (const float*)d_in[15];
    const float* w_l3 = (const float*)d_in[16];
    const float* b3   = (const float*)d_in[17];
    const float* w_r3 = (const float*)d_in[18];
    float* out = (float*)d_out;

    const int N = NNODE, E = NEDGE;
    const int* srcI = ei;
    const int* dstI = ei + E;

    char* w = (char*)d_ws;
    auto alloc = [&](size_t bytes) { void* p = (void*)w; w += (bytes + 255) & ~(size_t)255; return p; };
    int* deg = (int*)alloc((size_t)N * 4);
    int* rs  = (int*)alloc((size_t)(N + 1) * 4);
    int* cur = (int*)alloc((size_t)N * 4);
    int* csr = (int*)alloc((size_t)E * 4);
    unsigned short* xb   = (unsigned short*)alloc((size_t)N * 512 * 2);
    unsigned short* bt1  = (unsigned short*)alloc((size_t)512 * 1024 * 2);
    unsigned short* bt2  = (unsigned short*)alloc((size_t)512 * 1024 * 2);
    unsigned short* bt3  = (unsigned short*)alloc((size_t)256 * 1024 * 2);
    float* sc1 = (float*)alloc(512 * 4); float* sh1 = (float*)alloc(512 * 4);
    float* sc2 = (float*)alloc(512 * 4); float* sh2 = (float*)alloc(512 * 4);
    float* sc3 = (float*)alloc(256 * 4); float* sh3 = (float*)alloc(256 * 4);
    unsigned short* agg_a = (unsigned short*)alloc((size_t)N * 512 * 2);
    unsigned short* h1    = (unsigned short*)alloc((size_t)N * 512 * 2);
    unsigned short* h2    = (unsigned short*)alloc((size_t)N * 512 * 2);
    (void)alloc(256 * 1024);  // DMA over-read slack for last M-tile

    hipMemsetAsync(deg, 0, (size_t)N * 4, stream);
    k_prep<<<6906, 256, 0, stream>>>(x, xb, w_l1, w_r1, w_l2, w_r2, w_l3, w_r3,
                                     bt1, bt2, bt3,
                                     b1, g1, be1, m1, v1, b2, g2, be2, m2, v2, b3,
                                     sc1, sh1, sc2, sh2, sc3, sh3, dstI, deg);
    k_scan<<<1, 1024, 0, stream>>>(deg, rs, cur, N, E);
    k_fill<<<(E + 255) / 256, 256, 0, stream>>>(srcI, dstI, E, cur, csr);

    dim3 ga(N, 2);

    // Layer 1
    k_agg<<<ga, 64, 0, stream>>>(xb, rs, csr, agg_a);
    k_gemm<0, 512><<<320, 256, 0, stream>>>(agg_a, xb, bt1, sc1, sh1, h1, nullptr, N);
    // Layer 2
    k_agg<<<ga, 64, 0, stream>>>(h1, rs, csr, agg_a);
    k_gemm<0, 512><<<320, 256, 0, stream>>>(agg_a, h1, bt2, sc2, sh2, h2, nullptr, N);
    // Layer 3
    k_agg<<<ga, 64, 0, stream>>>(h2, rs, csr, agg_a);
    k_gemm<1, 256><<<160, 256, 0, stream>>>(agg_a, h2, bt3, sc3, sh3, nullptr, out, N);
}